// Round 6
// baseline (925.334 us; speedup 1.0000x reference)
//
#include <hip/hip_runtime.h>

#define BB 1024
#define TT 128
#define NBLK 256

using bf16   = __bf16;
using bf16x8 = __attribute__((ext_vector_type(8))) bf16;
using bf16x4 = __attribute__((ext_vector_type(4))) bf16;
using f32x4  = __attribute__((ext_vector_type(4))) float;

__device__ __forceinline__ float fsig(float x) {
  return __builtin_amdgcn_rcpf(1.f + __expf(-x));
}
__device__ __forceinline__ float ftanh(float x) {
  return 2.f * __builtin_amdgcn_rcpf(1.f + __expf(-2.f * x)) - 1.f;
}

// ---- coherent (cross-XCD, IF$-served) load/store helpers -------------------
__device__ __forceinline__ void st_i32_coh(int* p, int v) {
  __hip_atomic_store(p, v, __ATOMIC_RELAXED, __HIP_MEMORY_SCOPE_AGENT);
}
__device__ __forceinline__ int ld_i32_coh(const int* p) {
  return __hip_atomic_load((int*)p, __ATOMIC_RELAXED, __HIP_MEMORY_SCOPE_AGENT);
}
__device__ __forceinline__ float ld_f32_coh(const float* p) {
  return __hip_atomic_load((float*)p, __ATOMIC_RELAXED, __HIP_MEMORY_SCOPE_AGENT);
}
__device__ __forceinline__ void st_f32_coh(float* p, float v) {
  __hip_atomic_store(p, v, __ATOMIC_RELAXED, __HIP_MEMORY_SCOPE_AGENT);
}
__device__ __forceinline__ void st_u16_coh(unsigned short* p, unsigned short v) {
  __hip_atomic_store(p, v, __ATOMIC_RELAXED, __HIP_MEMORY_SCOPE_AGENT);
}
__device__ __forceinline__ bf16x8 ld_bf16x8_coh(const bf16* p) {
  union { unsigned long long u[2]; bf16x8 v; } c;
  c.u[0] = __hip_atomic_load((unsigned long long*)p, __ATOMIC_RELAXED, __HIP_MEMORY_SCOPE_AGENT);
  c.u[1] = __hip_atomic_load((unsigned long long*)(p + 4), __ATOMIC_RELAXED, __HIP_MEMORY_SCOPE_AGENT);
  return c.v;
}

// ---------------------------------------------------------------------------
// x_convert: x f32 [B,T,256] -> bf16 [T, row'(b), 256], row-permuted:
//   b = 256q + 16rt + i  ->  row' = rt*64 + q*16 + i.  Pure BW, no LDS.
// ALSO zeroes the barrier slot array every launch (the harness's fresh-launch
// tripwires run WITHOUT re-poisoning d_ws, so slots may hold last launch's
// final generation — they must be reset in-stream before dnc_main).
// ---------------------------------------------------------------------------
__global__ void x_convert(const float* __restrict__ x, bf16* __restrict__ x_bf,
                          int* __restrict__ slots) {
  const int tid = threadIdx.x, bid = blockIdx.x;
  if (bid == 0) {
    for (int e = tid; e < 4096; e += 256) st_i32_coh(slots + e, 0);
  }
  const int lane = tid & 63, wv = tid >> 6;
  const int wg = bid * 4 + wv;  // 0..8191
#pragma unroll 4
  for (int r = 0; r < 16; ++r) {
    int rid = wg + r * 8192;            // rid = b*T + t
    int b = rid >> 7, t = rid & 127;
    int rowp = ((b >> 4) & 15) * 64 + (b >> 8) * 16 + (b & 15);
    const float4 v = *(const float4*)(x + (size_t)rid * 256 + lane * 4);
    bf16x4 o;
    o[0] = (bf16)v.x; o[1] = (bf16)v.y; o[2] = (bf16)v.z; o[3] = (bf16)v.w;
    *(bf16x4*)(x_bf + ((size_t)t * BB + rowp) * 256 + lane * 4) = o;
  }
}

// ---------------------------------------------------------------------------
// persistent main: 256 blocks x 256 threads.  Phase A (block-local, no grid
// sync): stage Wx/Whh, per-block softmax -> smT (mem_sm^T bf16), WM tile via
// MFMA directly into sWM, G0 (32 owned values), FM, bias.  Main loop: one
// single-hop barrier per step (wave-0 batched polling), double-buffered h,
// pointwise in MFMA register layout.
// ---------------------------------------------------------------------------
__global__ void __launch_bounds__(256, 1) dnc_main(
    const bf16* __restrict__ x_bf, const float* __restrict__ memf,
    const float* __restrict__ rv0,
    const float* __restrict__ W_ih, const float* __restrict__ W_hh,
    const float* __restrict__ b_ih, const float* __restrict__ b_hh,
    const float* __restrict__ fc_w, const float* __restrict__ fc_b,
    bf16* __restrict__ hbuf0, bf16* __restrict__ hbuf1,
    float* __restrict__ hsumG, int* __restrict__ slots,
    float* __restrict__ out) {
  __shared__ bf16 sWx[32][264];    // Wx  (32 owned gate cols) x K=256 (+8 pad)
  __shared__ bf16 sWhh[32][136];   // Whh x K=128
  __shared__ bf16 sWM[32][520];    // WM  x K=512 (computed in phase A)
  __shared__ bf16 sHq[16][520];    // hquad-major staged tile
  __shared__ bf16 smT[128][136];   // mem_sm^T: smT[n][m]
  __shared__ float sFM[2][512];
  __shared__ float sG0[32];        // [gate c (4)][owned col jj (8)]

  const int bid = blockIdx.x, tid = threadIdx.x;
  const int rt = bid >> 4, gt = bid & 15;
  const int wave = tid >> 6, lane = tid & 63;
  const int l15 = lane & 15, l4 = lane >> 4;

  auto gcol = [&](int pos) { return ((pos >> 3) << 7) + gt * 8 + (pos & 7); };

  // ---- Phase A -------------------------------------------------------------
  for (int e = tid; e < 32 * 256; e += 256) sWx[e >> 8][e & 255] = (bf16)W_ih[(size_t)gcol(e >> 8) * 768 + (e & 255)];
  for (int e = tid; e < 32 * 128; e += 256) sWhh[e >> 7][e & 127] = (bf16)W_hh[gcol(e >> 7) * 128 + (e & 127)];
  if (tid < 128) {  // column softmax + smT + FM
    const int n = tid;
    float mx = -1e30f;
    for (int m = 0; m < 128; ++m) mx = fmaxf(mx, memf[m * 128 + n]);
    float s = 0.f;
    for (int m = 0; m < 128; ++m) s += __expf(memf[m * 128 + n] - mx);
    float inv = __builtin_amdgcn_rcpf(s);
    float fa[8] = {0.f, 0.f, 0.f, 0.f, 0.f, 0.f, 0.f, 0.f};
#pragma unroll 4
    for (int m = 0; m < 128; ++m) {
      float e = __expf(memf[m * 128 + n] - mx) * inv;
      smT[n][m] = (bf16)e;
#pragma unroll
      for (int o = 0; o < 2; ++o)
#pragma unroll
        for (int r = 0; r < 4; ++r) fa[o * 4 + r] += e * fc_w[o * 640 + 128 + r * 128 + m];
    }
#pragma unroll
    for (int o = 0; o < 2; ++o)
#pragma unroll
      for (int r = 0; r < 4; ++r) sFM[o][r * 128 + n] = fa[o * 4 + r];
  }
  if (tid < 32) {  // G0 owned values
    const int c = tid >> 3, jj = tid & 7;
    const float* wr = W_ih + (size_t)(c * 128 + gt * 8 + jj) * 768 + 256;
    float acc = 0.f;
#pragma unroll 4
    for (int k4 = 0; k4 < 128; ++k4) {
      float4 a = *(const float4*)(rv0 + k4 * 4);
      float4 b = *(const float4*)(wr + k4 * 4);
      acc += a.x * b.x + a.y * b.y + a.z * b.z + a.w * b.w;
    }
    sG0[tid] = acc;
  }
  __syncthreads();  // smT ready
  // WM tile via MFMA into sWM
#pragma unroll
  for (int r = 0; r < 4; ++r) {
    bf16x8 afr[2][4];
#pragma unroll
    for (int g = 0; g < 2; ++g)
#pragma unroll
      for (int kk = 0; kk < 4; ++kk) {
        const float* ap = W_ih + (size_t)gcol(g * 16 + l15) * 768 + 256 + r * 128 + kk * 32 + l4 * 8;
        float4 p0 = *(const float4*)ap, p1 = *(const float4*)(ap + 4);
        bf16x8 f;
        f[0] = (bf16)p0.x; f[1] = (bf16)p0.y; f[2] = (bf16)p0.z; f[3] = (bf16)p0.w;
        f[4] = (bf16)p1.x; f[5] = (bf16)p1.y; f[6] = (bf16)p1.z; f[7] = (bf16)p1.w;
        afr[g][kk] = f;
      }
#pragma unroll
    for (int nto = 0; nto < 2; ++nto) {
      const int nt = wave * 2 + nto;
      f32x4 a0 = {0.f, 0.f, 0.f, 0.f}, a1 = {0.f, 0.f, 0.f, 0.f};
#pragma unroll
      for (int kk = 0; kk < 4; ++kk) {
        bf16x8 b = *(const bf16x8*)&smT[nt * 16 + l15][kk * 32 + l4 * 8];
        a0 = __builtin_amdgcn_mfma_f32_16x16x32_bf16(afr[0][kk], b, a0, 0, 0, 0);
        a1 = __builtin_amdgcn_mfma_f32_16x16x32_bf16(afr[1][kk], b, a1, 0, 0, 0);
      }
#pragma unroll
      for (int reg = 0; reg < 4; ++reg) {
        sWM[l4 * 4 + reg][r * 128 + nt * 16 + l15]      = (bf16)a0[reg];
        sWM[16 + l4 * 4 + reg][r * 128 + nt * 16 + l15] = (bf16)a1[reg];
      }
    }
  }
  __syncthreads();  // sWM ready

  const float bv0 = b_ih[gcol(l15)] + b_hh[gcol(l15)];
  const float bv1 = b_ih[gcol(16 + l15)] + b_hh[gcol(16 + l15)];

  // pointwise cell ownership (register layout)
  const bool lo = (l15 < 8);
  const int j = l15 & 7;
  const int rb = lo ? 0 : 2;
  float cst[2] = {0.f, 0.f}, hsum[2] = {0.f, 0.f};
  int growp[2];
#pragma unroll
  for (int k = 0; k < 2; ++k) growp[k] = rt * 16 + (l4 * 4 + rb + k) + 256 * wave;

  f32x4 acc0, acc1;

  auto xpart = [&](int t) {
    acc0 = f32x4{bv0, bv0, bv0, bv0};
    acc1 = f32x4{bv1, bv1, bv1, bv1};
    const bf16* xr = x_bf + ((size_t)t * BB + rt * 64 + wave * 16 + l15) * 256 + l4 * 8;
#pragma unroll
    for (int kk = 0; kk < 8; ++kk) {
      bf16x8 a  = *(const bf16x8*)(xr + kk * 32);
      bf16x8 w0 = *(const bf16x8*)&sWx[l15][kk * 32 + l4 * 8];
      bf16x8 w1 = *(const bf16x8*)&sWx[16 + l15][kk * 32 + l4 * 8];
      acc0 = __builtin_amdgcn_mfma_f32_16x16x32_bf16(a, w0, acc0, 0, 0, 0);
      acc1 = __builtin_amdgcn_mfma_f32_16x16x32_bf16(a, w1, acc1, 0, 0, 0);
    }
  };

  auto hpart = [&](const bf16* hrd) {
    bf16x8 ha[4];
    const bf16* hr = hrd + (size_t)(rt * 16 + l15 + 256 * wave) * 128 + l4 * 8;
#pragma unroll
    for (int kk = 0; kk < 4; ++kk) ha[kk] = ld_bf16x8_coh(hr + kk * 32);
#pragma unroll
    for (int pass = 0; pass < 4; ++pass) {
      int row = (tid >> 4) + 16 * pass, seg = tid & 15;
      bf16x8 v = ld_bf16x8_coh(hrd + (size_t)(rt * 64 + row) * 128 + seg * 8);
      *(bf16x8*)&sHq[row >> 2][(row & 3) * 128 + seg * 8] = v;
    }
#pragma unroll
    for (int kk = 0; kk < 4; ++kk) {
      bf16x8 w0 = *(const bf16x8*)&sWhh[l15][kk * 32 + l4 * 8];
      bf16x8 w1 = *(const bf16x8*)&sWhh[16 + l15][kk * 32 + l4 * 8];
      acc0 = __builtin_amdgcn_mfma_f32_16x16x32_bf16(ha[kk], w0, acc0, 0, 0, 0);
      acc1 = __builtin_amdgcn_mfma_f32_16x16x32_bf16(ha[kk], w1, acc1, 0, 0, 0);
    }
    __syncthreads();  // sHq ready
#pragma unroll
    for (int kk = 0; kk < 16; ++kk) {
      bf16x8 a  = *(const bf16x8*)&sHq[l15][kk * 32 + l4 * 8];
      bf16x8 w0 = *(const bf16x8*)&sWM[l15][kk * 32 + l4 * 8];
      bf16x8 w1 = *(const bf16x8*)&sWM[16 + l15][kk * 32 + l4 * 8];
      acc0 = __builtin_amdgcn_mfma_f32_16x16x32_bf16(a, w0, acc0, 0, 0, 0);
      acc1 = __builtin_amdgcn_mfma_f32_16x16x32_bf16(a, w1, acc1, 0, 0, 0);
    }
  };

  auto pw = [&](bool add_g0, bf16* hwr) {
    float o0[4], o1[4];
#pragma unroll
    for (int r = 0; r < 4; ++r) {
      o0[r] = __shfl_xor(acc0[r], 8);
      o1[r] = __shfl_xor(acc1[r], 8);
    }
    float g0i = 0.f, g0f = 0.f, g0g = 0.f, g0o = 0.f;
    if (add_g0) {
      g0i = sG0[j]; g0f = sG0[8 + j]; g0g = sG0[16 + j]; g0o = sG0[24 + j];
    }
#pragma unroll
    for (int k = 0; k < 2; ++k) {
      int r = rb + k;
      float gi = (lo ? acc0[r] : o0[r]) + g0i;
      float gf = (lo ? o0[r] : acc0[r]) + g0f;
      float gg = (lo ? acc1[r] : o1[r]) + g0g;
      float go = (lo ? o1[r] : acc1[r]) + g0o;
      cst[k] = fsig(gf) * cst[k] + fsig(gi) * ftanh(gg);
      float h = fsig(go) * ftanh(cst[k]);
      hsum[k] += h;
      union { bf16 b; unsigned short u; } cv; cv.b = (bf16)h;
      st_u16_coh((unsigned short*)(hwr + (size_t)growp[k] * 128 + gt * 8 + j), cv.u);
    }
  };

  auto commit = [&](int gen) {
    asm volatile("s_waitcnt vmcnt(0)" ::: "memory");
    __syncthreads();
    if (tid == 0) st_i32_coh(slots + bid * 16, gen);
  };
  auto gridwait = [&](int gen) {
    // wave 0 polls all 256 slots (4 per lane, batched); other waves park.
    if (wave == 0) {
      int s0, s1, s2, s3;
      do {
        s0 = ld_i32_coh(slots + lane * 16);
        s1 = ld_i32_coh(slots + (lane + 64) * 16);
        s2 = ld_i32_coh(slots + (lane + 128) * 16);
        s3 = ld_i32_coh(slots + (lane + 192) * 16);
      } while (min(min(s0, s1), min(s2, s3)) < gen);
    }
    __syncthreads();
  };

  // ---- timeline: one barrier per step, double-buffered h ------------------
  xpart(0);
  pw(true, hbuf0);   // h_0 -> buf0 (h(-1)=0; G-path = G0)
  commit(1);
  for (int t = 1; t < TT; ++t) {
    xpart(t);                              // h-independent, overlaps stragglers
    gridwait(t);                           // all blocks committed h_{t-1}
    hpart((t & 1) ? hbuf0 : hbuf1);        // read h_{t-1}
    pw(false, (t & 1) ? hbuf1 : hbuf0);    // write h_t
    commit(t + 1);
  }
  // epilogue: hsum -> global, barrier, fused mean+projection
#pragma unroll
  for (int k = 0; k < 2; ++k)
    st_f32_coh(hsumG + (size_t)growp[k] * 128 + gt * 8 + j, hsum[k]);
  commit(TT + 1);
  gridwait(TT + 1);
  {
    int row = bid * 4 + wave;
    const float* hsr = hsumG + (size_t)row * 128;
    const float* hqr = hsumG + (size_t)(row & 255) * 512;
    float s0 = 0.f, s1 = 0.f;
    for (int k = lane; k < 128; k += 64) { float v = ld_f32_coh(hsr + k); s0 += v * fc_w[k]; s1 += v * fc_w[640 + k]; }
    for (int k = lane; k < 512; k += 64) { float v = ld_f32_coh(hqr + k); s0 += v * sFM[0][k]; s1 += v * sFM[1][k]; }
    for (int off = 32; off > 0; off >>= 1) { s0 += __shfl_down(s0, off); s1 += __shfl_down(s1, off); }
    if (lane == 0) {
      out[row * 2 + 0] = s0 * (1.f / 128.f) + fc_b[0];
      out[row * 2 + 1] = s1 * (1.f / 128.f) + fc_b[1];
    }
  }
}

// ---------------------------------------------------------------------------
extern "C" void kernel_launch(void* const* d_in, const int* in_sizes, int n_in,
                              void* d_out, int out_size, void* d_ws, size_t ws_size,
                              hipStream_t stream) {
  const float* x      = (const float*)d_in[0];
  const float* memory = (const float*)d_in[1];
  const float* rv0    = (const float*)d_in[2];
  const float* W_ih   = (const float*)d_in[3];
  const float* W_hh   = (const float*)d_in[4];
  const float* b_ih   = (const float*)d_in[5];
  const float* b_hh   = (const float*)d_in[6];
  const float* fc_w   = (const float*)d_in[7];
  const float* fc_b   = (const float*)d_in[8];
  float* out = (float*)d_out;
  char* ws = (char*)d_ws;

  bf16* x_bf   = (bf16*)ws;                     // 67,108,864 B
  bf16* hbuf0  = (bf16*)(ws + 67108864);        //    262,144
  bf16* hbuf1  = (bf16*)(ws + 67371008);        //    262,144
  int*  slots  = (int*)(ws + 67633152);         //     16,384
  float* hsumG = (float*)(ws + 67649536);       //    524,288

  x_convert<<<2048, 256, 0, stream>>>(x, x_bf, slots);
  dnc_main<<<NBLK, 256, 0, stream>>>(x_bf, memory, rv0, W_ih, W_hh, b_ih, b_hh,
                                     fc_w, fc_b, hbuf0, hbuf1, hsumG, slots, out);
}